// Round 1
// baseline (3961.850 us; speedup 1.0000x reference)
//
#include <hip/hip_runtime.h>
#include <hip/hip_bf16.h>

#define BN 2
#define CH 256
#define HH 96
#define WW 96
#define NL 4
#define HW (HH*WW)
#define KK (CH*9)   // 2304

// dw (L, O, C, 3, 3) -> wT[l][j][o], j = c*9 + k  (k = ky*3+kx)
__global__ void wt_kernel(const float* __restrict__ dw, float* __restrict__ wT) {
    int idx = blockIdx.x * blockDim.x + threadIdx.x;
    if (idx >= NL * KK * CH) return;
    int o = idx & (CH - 1);
    int j = (idx >> 8) % KK;
    int l = idx / (KK * CH);
    int c = j / 9;
    int k = j - 9 * c;
    wT[idx] = dw[((size_t)(l * CH + o) * CH + c) * 9 + k];
}

// off[b][oc][h][w] = bias[oc] + sum_{c,ky,kx} x[b][c][h+ky-1][w+kx-1] * ow[oc][c][ky][kx]
__global__ void off_conv_kernel(const float* __restrict__ x,
                                const float* __restrict__ ow,
                                const float* __restrict__ ob,
                                float* __restrict__ off) {
    int idx = blockIdx.x * blockDim.x + threadIdx.x;
    if (idx >= BN * 18 * HW) return;
    int w  = idx % WW;
    int h  = (idx / WW) % HH;
    int oc = (idx / HW) % 18;
    int b  = idx / (18 * HW);
    float acc = ob[oc];
    const float* xb = x + (size_t)b * CH * HW;
    const float* wp = ow + (size_t)oc * CH * 9;
    for (int c = 0; c < CH; ++c) {
        const float* xc = xb + c * HW;
        const float* wc = wp + c * 9;
        #pragma unroll
        for (int ky = 0; ky < 3; ++ky) {
            int y = h + ky - 1;
            if ((unsigned)y >= HH) continue;
            const float* xr = xc + y * WW;
            #pragma unroll
            for (int kx = 0; kx < 3; ++kx) {
                int xw = w + kx - 1;
                if ((unsigned)xw >= WW) continue;
                acc = fmaf(xr[xw], wc[ky * 3 + kx], acc);
            }
        }
    }
    off[idx] = acc;
}

// One block = 4 spatial positions, 256 threads (thread = output channel).
// Phase 1: bilinear-sample 4*2304 values into LDS, layout sam[j*4+p].
// Phase 2: GEMM j-loop: broadcast ds_read_b128 + coalesced wT load + 4 FMA.
__global__ void __launch_bounds__(256)
deform_kernel(const float* __restrict__ x, const float* __restrict__ off,
              const float* __restrict__ wT, const float* __restrict__ bias,
              float* __restrict__ out) {
    __shared__ __align__(16) float sam[KK * 4];
    __shared__ float offs[4][18];
    const int tid = threadIdx.x;
    const int pos0 = blockIdx.x * 4;

    if (tid < 72) {
        int p = tid / 18, i = tid - 18 * (tid / 18);
        int pos = pos0 + p;
        int w = pos % WW, h = (pos / WW) % HH, b = pos / HW;
        offs[p][i] = off[((b * 18 + i) * HH + h) * WW + w];
    }
    __syncthreads();

    for (int it = 0; it < (4 * KK) / 256; ++it) {
        int idx = tid + it * 256;
        int p = idx & 3;
        int j = idx >> 2;
        int c = j / 9;
        int k = j - 9 * c;
        int ky = k / 3, kx = k - 3 * ky;
        int pos = pos0 + p;
        int w = pos % WW, h = (pos / WW) % HH, b = pos / HW;
        float py = (float)(h - 1 + ky) + offs[p][2 * k];
        float px = (float)(w - 1 + kx) + offs[p][2 * k + 1];
        float y0f = floorf(py), x0f = floorf(px);
        int y0 = (int)y0f, x0 = (int)x0f;
        int y1 = y0 + 1, x1 = x0 + 1;
        float wy1 = py - y0f, wy0 = 1.f - wy1;
        float wx1 = px - x0f, wx0 = 1.f - wx1;
        // validity folded into the per-axis weights (exact factorization of ref)
        float fy0 = ((unsigned)y0 < HH) ? wy0 : 0.f;
        float fy1 = ((unsigned)y1 < HH) ? wy1 : 0.f;
        float fx0 = ((unsigned)x0 < WW) ? wx0 : 0.f;
        float fx1 = ((unsigned)x1 < WW) ? wx1 : 0.f;
        int y0c = min(max(y0, 0), HH - 1), x0c = min(max(x0, 0), WW - 1);
        int y1c = min(max(y1, 0), HH - 1), x1c = min(max(x1, 0), WW - 1);
        const float* xc = x + ((size_t)b * CH + c) * HW;
        float v = (xc[y0c * WW + x0c] * fx0 + xc[y0c * WW + x1c] * fx1) * fy0
                + (xc[y1c * WW + x0c] * fx0 + xc[y1c * WW + x1c] * fx1) * fy1;
        sam[idx] = v;
    }
    __syncthreads();

    float acc0 = 0.f, acc1 = 0.f, acc2 = 0.f, acc3 = 0.f;
    const float* wp = wT + tid;
    #pragma unroll 8
    for (int j = 0; j < KK; ++j) {
        float4 s = *((const float4*)sam + j);
        float wv = wp[j << 8];
        acc0 = fmaf(wv, s.x, acc0);
        acc1 = fmaf(wv, s.y, acc1);
        acc2 = fmaf(wv, s.z, acc2);
        acc3 = fmaf(wv, s.w, acc3);
    }

    float bs = bias[tid];
    float accs[4] = {acc0, acc1, acc2, acc3};
    #pragma unroll
    for (int p = 0; p < 4; ++p) {
        int pos = pos0 + p;
        int w = pos % WW, h = (pos / WW) % HH, b = pos / HW;
        out[(((size_t)b * CH + tid) * HH + h) * WW + w] = fmaxf(accs[p] + bs, 0.f);
    }
}

extern "C" void kernel_launch(void* const* d_in, const int* in_sizes, int n_in,
                              void* d_out, int out_size, void* d_ws, size_t ws_size,
                              hipStream_t stream) {
    const float* x     = (const float*)d_in[0];
    const float* off_w = (const float*)d_in[1];
    const float* off_b = (const float*)d_in[2];
    const float* dw    = (const float*)d_in[3];
    const float* db    = (const float*)d_in[4];

    float* ws = (float*)d_ws;
    float* off_buf = ws;                          // BN*18*HW
    float* buf0    = off_buf + BN * 18 * HW;      // BN*CH*HW
    float* buf1    = buf0 + BN * CH * HW;         // BN*CH*HW
    float* wT      = buf1 + BN * CH * HW;         // NL*KK*CH

    wt_kernel<<<(NL * KK * CH + 255) / 256, 256, 0, stream>>>(dw, wT);

    const float* cur = x;
    for (int l = 0; l < NL; ++l) {
        float* nxt = (l == NL - 1) ? (float*)d_out : ((l & 1) ? buf1 : buf0);
        off_conv_kernel<<<(BN * 18 * HW + 255) / 256, 256, 0, stream>>>(
            cur, off_w + (size_t)l * 18 * CH * 9, off_b + l * 18, off_buf);
        deform_kernel<<<BN * HW / 4, 256, 0, stream>>>(
            cur, off_buf, wT + (size_t)l * KK * CH, db + l * CH, nxt);
        cur = nxt;
    }
}

// Round 2
// 891.505 us; speedup vs baseline: 4.4440x; 4.4440x over previous
//
#include <hip/hip_runtime.h>

#define BN 2
#define CH 256
#define HH 96
#define WW 96
#define NL 4
#define HW (HH*WW)        // 9216
#define KK (CH*9)         // 2304
#define NPOS (BN*HW)      // 18432

#define CKLEN 576         // K-chunk staged in LDS (4 chunks of 576 = 2304)
#define NCK 4
#define SAMW 592          // padded LDS row stride (bf16 elems) -> 4-way max on a_frag reads

#define NOCHK 16          // off-conv channel chunks
#define OCCH (CH/NOCHK)   // 16 channels per chunk

#define WB_PER_L (288*256*8)   // 589824 bf16 per layer, layout [k/8][oc][k%8]
#define WB_TOT (NL*WB_PER_L)
#define OWT_PER_L (KK*20)      // off weights transposed [c*9+k][oc pad 20]
#define OWT_TOT (NL*OWT_PER_L)

typedef __attribute__((ext_vector_type(8))) short short8;
typedef __attribute__((ext_vector_type(4))) float f32x4;

__device__ __forceinline__ unsigned short f2bf(float f) {
    union { float f; unsigned int u; } v; v.f = f;
    unsigned int r = v.u + 0x7fffu + ((v.u >> 16) & 1u);
    return (unsigned short)(r >> 16);
}

// Pack dw -> wB (bf16, B-fragment order) and off_w -> owT (f32, [c*9+k][oc pad 20])
__global__ void prep_kernel(const float* __restrict__ dw, const float* __restrict__ off_w,
                            unsigned short* __restrict__ wB, float* __restrict__ owT) {
    int idx = blockIdx.x * 256 + threadIdx.x;
    if (idx < WB_TOT) {
        int j  = idx & 7;
        int oc = (idx >> 3) & 255;
        int g  = (idx >> 11) % 288;
        int l  = idx / WB_PER_L;
        int k  = g * 8 + j;
        int c  = k / 9, t9 = k - 9 * c;
        wB[idx] = f2bf(dw[((size_t)(l * CH + oc) * CH + c) * 9 + t9]);
    } else {
        int i2 = idx - WB_TOT;
        if (i2 >= OWT_TOT) return;
        int ocp = i2 % 20;
        int r   = (i2 / 20) % KK;
        int l   = i2 / OWT_PER_L;
        int c   = r / 9, t9 = r - 9 * c;
        owT[i2] = (ocp < 18) ? off_w[((size_t)(l * 18 + ocp) * CH + c) * 9 + t9] : 0.f;
    }
}

// Offset conv, partial over 16-channel chunk. grid = 72 pos-blocks * 16 chunks.
// Thread = one position; 18(+2 pad) accumulators; weights staged in LDS as float4.
__global__ void __launch_bounds__(256)
off_conv2_kernel(const float* __restrict__ x, const float* __restrict__ owT,
                 float* __restrict__ part) {
    __shared__ __align__(16) float wch[OCCH * 180];   // 11520 B
    const int pb = blockIdx.x >> 4;
    const int cc = blockIdx.x & 15;
    const int tid = threadIdx.x;
    for (int i = tid; i < OCCH * 180; i += 256)
        wch[i] = owT[(size_t)(cc * OCCH) * 180 + i];

    const int pos = pb * 256 + tid;
    const int b = pos / HW, rem = pos - b * HW;
    const int h = rem / WW, w = rem - h * WW;
    int offk[9]; float mk[9];
    #pragma unroll
    for (int k = 0; k < 9; ++k) {
        int dy = k / 3 - 1, dx = k % 3 - 1;
        int yk = h + dy, xk = w + dx;
        bool valid = ((unsigned)yk < HH) && ((unsigned)xk < WW);
        offk[k] = min(max(yk, 0), HH - 1) * WW + min(max(xk, 0), WW - 1);
        mk[k] = valid ? 1.f : 0.f;
    }
    float acc[20];
    #pragma unroll
    for (int o = 0; o < 20; ++o) acc[o] = 0.f;
    __syncthreads();

    const float* xc = x + (size_t)(b * CH + cc * OCCH) * HW;
    for (int c = 0; c < OCCH; ++c, xc += HW) {
        float xv[9];
        #pragma unroll
        for (int k = 0; k < 9; ++k) xv[k] = xc[offk[k]] * mk[k];
        const float4* wr = (const float4*)&wch[c * 180];
        #pragma unroll
        for (int k = 0; k < 9; ++k) {
            #pragma unroll
            for (int o4 = 0; o4 < 5; ++o4) {
                float4 wv4 = wr[k * 5 + o4];
                acc[o4*4+0] = fmaf(xv[k], wv4.x, acc[o4*4+0]);
                acc[o4*4+1] = fmaf(xv[k], wv4.y, acc[o4*4+1]);
                acc[o4*4+2] = fmaf(xv[k], wv4.z, acc[o4*4+2]);
                acc[o4*4+3] = fmaf(xv[k], wv4.w, acc[o4*4+3]);
            }
        }
    }
    float* pp = part + (size_t)(cc * BN + b) * 18 * HW + rem;
    #pragma unroll
    for (int o = 0; o < 18; ++o) pp[(size_t)o * HW] = acc[o];
}

// Fused bilinear sampling + bf16 MFMA GEMM. Block = 16 positions (one row chunk)
// x 256 output channels. K staged in 4 chunks of 576 (LDS bf16, padded rows).
__global__ void __launch_bounds__(256)
deform_mfma_kernel(const float* __restrict__ x, const float* __restrict__ part,
                   const float* __restrict__ ob, const unsigned short* __restrict__ wB,
                   const float* __restrict__ db, float* __restrict__ out) {
    __shared__ __align__(16) unsigned short sam[16 * SAMW];   // 18944 B, reused as cT
    __shared__ float offs[16][18];
    const int tid  = threadIdx.x;
    const int pos0 = blockIdx.x * 16;
    const int b0   = pos0 / HW;
    const int rem0 = pos0 - b0 * HW;
    const int h0   = rem0 / WW;
    const int w0   = rem0 - h0 * WW;   // w0 % 16 == 0, so all 16 pos share (b0,h0)

    // offsets: sum 16 partial chunks + bias
    for (int i = tid; i < 16 * 18; i += 256) {
        int p = i / 18, oc = i - 18 * p;
        int hw = rem0 + p;
        float s = ob[oc];
        #pragma unroll
        for (int cc = 0; cc < NOCHK; ++cc)
            s += part[(size_t)(cc * BN + b0) * 18 * HW + (size_t)oc * HW + hw];
        offs[p][oc] = s;
    }

    const int m  = tid & 15;         // A row / B col within 16-tile
    const int q  = (tid >> 4) & 3;   // quad -> k = q*8+j
    const int wv = tid >> 6;         // wave -> oc quarter
    const int p_s = tid & 15;        // sampling position
    const int kq  = tid >> 4;        // 0..15
    const int w   = w0 + p_s;

    f32x4 acc[4] = {};
    const float* xb = x + (size_t)b0 * CH * HW;

    for (int ck = 0; ck < NCK; ++ck) {
        __syncthreads();
        // ---- sampling: 16 pos x 576 k -> LDS bf16 ----
        #pragma unroll 2
        for (int it = 0; it < 36; ++it) {
            int kk = it * 16 + kq;
            int k  = ck * CKLEN + kk;
            int c  = k / 9;
            int t9 = k - 9 * c;
            int ky = t9 / 3, kx = t9 - 3 * ky;
            float py = (float)(h0 - 1 + ky) + offs[p_s][2 * t9];
            float px = (float)(w  - 1 + kx) + offs[p_s][2 * t9 + 1];
            float yf = floorf(py), xf = floorf(px);
            int y0 = (int)yf, x0i = (int)xf;
            float wy1 = py - yf, wx1 = px - xf;
            float fy0 = ((unsigned)y0       < HH) ? 1.f - wy1 : 0.f;
            float fy1 = ((unsigned)(y0 + 1) < HH) ? wy1       : 0.f;
            float fx0 = ((unsigned)x0i      < WW) ? 1.f - wx1 : 0.f;
            float fx1 = ((unsigned)(x0i+1)  < WW) ? wx1       : 0.f;
            int y0c = min(max(y0, 0), HH - 1),     y1c = min(max(y0 + 1, 0), HH - 1);
            int x0c = min(max(x0i, 0), WW - 1),    x1c = min(max(x0i + 1, 0), WW - 1);
            const float* xc = xb + (size_t)c * HW;
            float v = (xc[y0c * WW + x0c] * fx0 + xc[y0c * WW + x1c] * fx1) * fy0
                    + (xc[y1c * WW + x0c] * fx0 + xc[y1c * WW + x1c] * fx1) * fy1;
            sam[p_s * SAMW + kk] = f2bf(v);
        }
        __syncthreads();
        // ---- GEMM on this chunk: 18 k-tiles of 32 ----
        const unsigned short* wp = wB + (size_t)(ck * 72 + q) * 256 * 8;
        for (int kb = 0; kb < 18; ++kb) {
            short8 av = *(const short8*)(sam + m * SAMW + kb * 32 + q * 8);
            const unsigned short* wkb = wp + (size_t)kb * 4 * 256 * 8;
            #pragma unroll
            for (int t = 0; t < 4; ++t) {
                short8 bv = *(const short8*)(wkb + (size_t)(wv * 64 + t * 16 + m) * 8);
                acc[t] = __builtin_amdgcn_mfma_f32_16x16x32_bf16(av, bv, acc[t], 0, 0, 0);
            }
        }
    }
    __syncthreads();
    // ---- epilogue: transpose through LDS for coalesced stores ----
    float* cT = (float*)sam;   // 256*17*4 = 17408 B <= 18944
    #pragma unroll
    for (int t = 0; t < 4; ++t) {
        int oc = wv * 64 + t * 16 + m;
        #pragma unroll
        for (int r = 0; r < 4; ++r)
            cT[oc * 17 + q * 4 + r] = acc[t][r];
    }
    __syncthreads();
    float bs = db[tid];
    float* op = out + (size_t)(b0 * CH + tid) * HW + h0 * WW + w0;
    #pragma unroll
    for (int i = 0; i < 4; ++i) {
        float4 v;
        v.x = fmaxf(cT[tid * 17 + 4 * i + 0] + bs, 0.f);
        v.y = fmaxf(cT[tid * 17 + 4 * i + 1] + bs, 0.f);
        v.z = fmaxf(cT[tid * 17 + 4 * i + 2] + bs, 0.f);
        v.w = fmaxf(cT[tid * 17 + 4 * i + 3] + bs, 0.f);
        *(float4*)(op + 4 * i) = v;
    }
}

extern "C" void kernel_launch(void* const* d_in, const int* in_sizes, int n_in,
                              void* d_out, int out_size, void* d_ws, size_t ws_size,
                              hipStream_t stream) {
    const float* x     = (const float*)d_in[0];
    const float* off_w = (const float*)d_in[1];
    const float* off_b = (const float*)d_in[2];
    const float* dw    = (const float*)d_in[3];
    const float* db    = (const float*)d_in[4];

    float* ws   = (float*)d_ws;
    float* part = ws;                                        // 16*BN*18*HW
    float* buf0 = part + (size_t)NOCHK * BN * 18 * HW;       // BN*CH*HW
    float* buf1 = buf0 + (size_t)BN * CH * HW;               // BN*CH*HW
    float* owT  = buf1 + (size_t)BN * CH * HW;               // OWT_TOT
    unsigned short* wB = (unsigned short*)(owT + OWT_TOT);   // WB_TOT bf16

    prep_kernel<<<(WB_TOT + OWT_TOT + 255) / 256, 256, 0, stream>>>(dw, off_w, wB, owT);

    const float* cur = x;
    for (int l = 0; l < NL; ++l) {
        float* nxt = (l == NL - 1) ? (float*)d_out : ((l & 1) ? buf1 : buf0);
        off_conv2_kernel<<<72 * NOCHK, 256, 0, stream>>>(
            cur, owT + (size_t)l * OWT_PER_L, part);
        deform_mfma_kernel<<<NPOS / 16, 256, 0, stream>>>(
            cur, part, off_b + l * 18, wB + (size_t)l * WB_PER_L, db + l * CH, nxt);
        cur = nxt;
    }
}